// Round 11
// baseline (414.564 us; speedup 1.0000x reference)
//
#include <hip/hip_runtime.h>
#include <hip/hip_bf16.h>
#include <stdint.h>

// GPTQ 4-bit linear: y = x @ dequant(qweight,qzeros,scales) + bias
// x: [4,2048,4096] fp32 -> M=8192 rows; qweight [512,4096] i32 (8 k-nibbles/word);
// qzeros [32,512] i32 (8 n-nibbles/word, z=nib+1); scales [32,4096] f32; out f32.

#define M_TOT 8192
#define N_TOT 4096
#define K_TOT 4096
#define NT    (K_TOT / 64)   // 64 K-tiles of BK=64

using bf16x8 = __attribute__((ext_vector_type(8))) __bf16;
using f32x4  = __attribute__((ext_vector_type(4))) float;

__device__ __forceinline__ unsigned short f2bf(float f) {
  unsigned u = __builtin_bit_cast(unsigned, f);
  u += 0x7fffu + ((u >> 16) & 1u);   // RNE
  return (unsigned short)(u >> 16);
}

// ---------------- x: fp32 -> bf16 ----------------
__global__ void cvt_x_kernel(const float* __restrict__ x,
                             unsigned short* __restrict__ xb, int n) {
  int stride = gridDim.x * blockDim.x * 8;
  for (int i = (blockIdx.x * blockDim.x + threadIdx.x) * 8; i < n; i += stride) {
    float4 a = *reinterpret_cast<const float4*>(x + i);
    float4 b = *reinterpret_cast<const float4*>(x + i + 4);
    unsigned short o[8] = {f2bf(a.x), f2bf(a.y), f2bf(a.z), f2bf(a.w),
                           f2bf(b.x), f2bf(b.y), f2bf(b.z), f2bf(b.w)};
    *reinterpret_cast<uint4*>(xb + i) = *reinterpret_cast<const uint4*>(o);
  }
}

// ---------------- dequant -> W^T [N][K] bf16 ----------------
__global__ void dequant_wt_kernel(const int* __restrict__ qweight,
                                  const int* __restrict__ qzeros,
                                  const float* __restrict__ scales,
                                  unsigned short* __restrict__ wt) {
  int t = blockIdx.x * blockDim.x + threadIdx.x;  // [0, N_TOT*512)
  int nn = t >> 9;
  int kw = t & 511;
  int g  = kw >> 4;
  unsigned w = (unsigned)qweight[kw * N_TOT + nn];
  float s = scales[g * N_TOT + nn];
  unsigned zw = (unsigned)qzeros[g * (N_TOT / 8) + (nn >> 3)];
  float z = (float)(((zw >> ((nn & 7) * 4)) & 15u) + 1u);
  unsigned short o[8];
#pragma unroll
  for (int j = 0; j < 8; ++j) {
    float v = s * ((float)((w >> (4 * j)) & 15u) - z);
    o[j] = f2bf(v);
  }
  *reinterpret_cast<uint4*>(wt + (size_t)nn * K_TOT + kw * 8) =
      *reinterpret_cast<const uint4*>(o);
}

// -- 256x256 GEMM: A via LDS (shared across waves), B direct global->reg -----
// B-fragment rows are wave-unique -> LDS staging of B was pure overhead.
// LDS/tile: reads 128 b128 (A only), writes 32 KB; 1 barrier/tile.
__device__ __forceinline__ void gll16(const unsigned short* g, const unsigned short* l) {
  __builtin_amdgcn_global_load_lds(
      (const __attribute__((address_space(1))) void*)(uintptr_t)g,
      (__attribute__((address_space(3))) void*)(uintptr_t)l, 16, 0, 0);
}

__global__ __launch_bounds__(512, 2) void gemm_breg_kernel(
    const unsigned short* __restrict__ A,   // [M_TOT][K_TOT] bf16
    const unsigned short* __restrict__ B,   // [N_TOT][K_TOT] bf16 (W^T)
    const float* __restrict__ bias,
    float* __restrict__ C) {
  __shared__ __align__(16) unsigned short As[2 * 256 * 64];   // 64 KB, A only

  int bid = blockIdx.x;                    // 512 blocks, 512 % 8 == 0
  int swz = (bid & 7) * 64 + (bid >> 3);   // bijective XCD swizzle (T1)
  int bm = swz & 31, bn = swz >> 5;        // 32 x 16 tiles
  int m0 = bm * 256, n0 = bn * 256;

  int t = threadIdx.x;
  int lane = t & 63;
  int wave = t >> 6;                       // 8 waves
  int wr = wave >> 2, wc = wave & 3;       // 2 (M) x 4 (N)
  int lr = lane & 15, kq = lane >> 4;

  // A staging (round-3 verified, 0 conflicts): physical chunk p = t&7 of rows
  // rowL0, rowL0+64; source pre-permuted j_log = (t&7) ^ (rowL0&7).
  int rowL0 = t >> 3;
  int jlog  = ((t & 7) ^ (rowL0 & 7)) * 8;
  const unsigned short* aG = A + (size_t)(m0 + rowL0) * K_TOT + jlog;

  // A swizzled read base; s half-select composed with XOR (round-2 lesson).
  unsigned rbA = (unsigned)((wr * 128 + lr) * 128 + ((kq * 16) ^ ((lr & 7) << 4)));

  // B direct-load base: row n0 + wc*64 + n*16 + lr, k-chunk kq*8 + s*32 +
  // tile*64 (same elements the LDS path delivered: logical chunk kq + 4s).
  const unsigned short* bRow = B + (size_t)(n0 + wc * 64 + lr) * K_TOT + kq * 8;

  f32x4 acc[8][4] = {};
  bf16x8 av[2][2][2];   // [pingpong][mm][s] — next-phase A frags
  bf16x8 bh[2][4][2];   // [tile parity][n][s] — B frags from GLOBAL, dbuf

#define ASTAGE(tile, h)                                                           \
  do {                                                                            \
    const unsigned short* _g = aG + (size_t)(h) * 128 * K_TOT +                   \
                               (size_t)(tile) * 64;                               \
    const unsigned short* _l = As + ((tile) & 1) * 16384 + (h) * 8192 + t * 8;    \
    gll16(_g, _l);                                                                \
    gll16(_g + (size_t)64 * K_TOT, _l + 4096);                                    \
  } while (0)

#define BLOAD(par, tile)                                                          \
  do {                                                                            \
    _Pragma("unroll")                                                             \
    for (int _n = 0; _n < 4; ++_n)                                                \
      _Pragma("unroll")                                                           \
      for (int _s = 0; _s < 2; ++_s)                                              \
        bh[par][_n][_s] = *(const bf16x8*)(bRow + (size_t)_n * 16 * K_TOT +       \
                                           (size_t)(tile) * 64 + _s * 32);        \
  } while (0)

  // Prologue: stage A(0), load B(0) to regs.
  ASTAGE(0, 0);
  ASTAGE(0, 1);
  BLOAD(0, 0);
  asm volatile("s_waitcnt vmcnt(0)" ::: "memory");
  __builtin_amdgcn_s_barrier();
  __builtin_amdgcn_sched_barrier(0);

  // Preload tile-0 phase-0 A frags.
#pragma unroll
  for (int mm = 0; mm < 2; ++mm)
#pragma unroll
    for (int s = 0; s < 2; ++s)
      av[0][mm][s] = *(const bf16x8*)((const char*)As + ((rbA + mm * 2048) ^ (s * 64)));

#pragma unroll 2
  for (int tt = 0; tt < NT; ++tt) {
    const char* aBuf = (const char*)As + (tt & 1) * 32768;

#pragma unroll
    for (int q = 0; q < 4; ++q) {
      // --- MFMA on operands prefetched last phase ---
      __builtin_amdgcn_s_setprio(1);
#pragma unroll
      for (int s = 0; s < 2; ++s)
#pragma unroll
        for (int mm = 0; mm < 2; ++mm)
#pragma unroll
          for (int n = 0; n < 4; ++n)
            acc[2 * q + mm][n] = __builtin_amdgcn_mfma_f32_16x16x32_bf16(
                av[q & 1][mm][s], bh[tt & 1][n][s], acc[2 * q + mm][n], 0, 0, 0);
      __builtin_amdgcn_s_setprio(0);

      // --- prefetch next phase's A frags (A stages write other parity) ---
      if (q < 3) {
#pragma unroll
        for (int mm = 0; mm < 2; ++mm)
#pragma unroll
          for (int s = 0; s < 2; ++s)
            av[(q + 1) & 1][mm][s] = *(const bf16x8*)(
                aBuf + ((rbA + (2 * (q + 1) + mm) * 2048) ^ (s * 64)));
      }

      // --- issue next tile's loads early (4 phases of latency cover) ---
      if (q == 0 && tt + 1 < NT) {
        BLOAD((tt + 1) & 1, tt + 1);   // B(t+1) -> regs (writes idle bank)
        ASTAGE(tt + 1, 0);             // A(t+1)h0 -> opposite LDS parity
      }
      if (q == 1 && tt + 1 < NT) ASTAGE(tt + 1, 1);

      if (q == 3) {
        // All outstanding loads (B(t+1) regs + A(t+1) glls) were issued
        // >=2 phases (~1300 cyc) ago -> this drain is cheap. Single barrier
        // per tile publishes A(t+1) for the cross-read below.
        asm volatile("s_waitcnt vmcnt(0)" ::: "memory");
        __builtin_amdgcn_s_barrier();
        __builtin_amdgcn_sched_barrier(0);
        if (tt + 1 < NT) {
          const char* aN = (const char*)As + ((tt + 1) & 1) * 32768;
#pragma unroll
          for (int mm = 0; mm < 2; ++mm)
#pragma unroll
            for (int s = 0; s < 2; ++s)
              av[0][mm][s] = *(const bf16x8*)(aN + ((rbA + mm * 2048) ^ (s * 64)));
        }
      }
    }
  }
#undef ASTAGE
#undef BLOAD

  // Epilogue: C/D layout col=lane&15, row=(lane>>4)*4+reg (m89-verified).
#pragma unroll
  for (int n = 0; n < 4; ++n) {
    int ncol = n0 + wc * 64 + n * 16 + lr;
    float bz = bias[ncol];
#pragma unroll
    for (int m = 0; m < 8; ++m) {
      int mrow = m0 + wr * 128 + m * 16 + kq * 4;
#pragma unroll
      for (int r = 0; r < 4; ++r)
        C[(size_t)(mrow + r) * N_TOT + ncol] = acc[m][n][r] + bz;
    }
  }
}

extern "C" void kernel_launch(void* const* d_in, const int* in_sizes, int n_in,
                              void* d_out, int out_size, void* d_ws, size_t ws_size,
                              hipStream_t stream) {
  const float* x       = (const float*)d_in[0];
  const int*   qweight = (const int*)d_in[1];
  const int*   qzeros  = (const int*)d_in[2];
  const float* scales  = (const float*)d_in[3];
  const float* bias    = (const float*)d_in[4];
  float* out = (float*)d_out;

  const size_t xb_bytes = (size_t)M_TOT * K_TOT * 2;   // 64 MB
  const size_t wt_bytes = (size_t)N_TOT * K_TOT * 2;   // 32 MB
  if (ws_size < xb_bytes + wt_bytes) return;

  unsigned short* Xb = (unsigned short*)d_ws;
  unsigned short* Wt = (unsigned short*)((char*)d_ws + xb_bytes);

  cvt_x_kernel<<<2048, 256, 0, stream>>>(x, Xb, M_TOT * K_TOT);
  dequant_wt_kernel<<<(N_TOT * 512) / 256, 256, 0, stream>>>(qweight, qzeros, scales, Wt);

  dim3 grid((M_TOT / 256) * (N_TOT / 256));  // 512
  gemm_breg_kernel<<<grid, 512, 0, stream>>>(Xb, Wt, bias, out);
}

// Round 12
// 284.933 us; speedup vs baseline: 1.4550x; 1.4550x over previous
//
#include <hip/hip_runtime.h>
#include <hip/hip_bf16.h>
#include <stdint.h>

// GPTQ 4-bit linear: y = x @ dequant(qweight,qzeros,scales) + bias
// x: [4,2048,4096] fp32 -> M=8192 rows; qweight [512,4096] i32 (8 k-nibbles/word);
// qzeros [32,512] i32 (8 n-nibbles/word, z=nib+1); scales [32,4096] f32; out f32.

#define M_TOT 8192
#define N_TOT 4096
#define K_TOT 4096
#define NT    (K_TOT / 64)   // 64 K-tiles of BK=64

using bf16x8 = __attribute__((ext_vector_type(8))) __bf16;
using f32x4  = __attribute__((ext_vector_type(4))) float;

__device__ __forceinline__ unsigned short f2bf(float f) {
  unsigned u = __builtin_bit_cast(unsigned, f);
  u += 0x7fffu + ((u >> 16) & 1u);   // RNE
  return (unsigned short)(u >> 16);
}

// ---------------- x: fp32 -> bf16 ----------------
__global__ void cvt_x_kernel(const float* __restrict__ x,
                             unsigned short* __restrict__ xb, int n) {
  int stride = gridDim.x * blockDim.x * 8;
  for (int i = (blockIdx.x * blockDim.x + threadIdx.x) * 8; i < n; i += stride) {
    float4 a = *reinterpret_cast<const float4*>(x + i);
    float4 b = *reinterpret_cast<const float4*>(x + i + 4);
    unsigned short o[8] = {f2bf(a.x), f2bf(a.y), f2bf(a.z), f2bf(a.w),
                           f2bf(b.x), f2bf(b.y), f2bf(b.z), f2bf(b.w)};
    *reinterpret_cast<uint4*>(xb + i) = *reinterpret_cast<const uint4*>(o);
  }
}

// -------- dequant -> W^T packed in MFMA fragment order ----------------------
// Element layout (ushort): P[bn][wc][t][n*2+s][lane][j], strides (elems):
// bn:1048576? no -> bn*4+wc: 262144, t: 4096, frag: 512, lane: 8, j: 1.
// GEMM wave (bn,wc) tile t frag (n,s): lane l holds W^T[nn][k], nn =
// bn*256+wc*64+n*16+(l&15), k = t*64+s*32+(l>>4)*8+j. Dequant thread u owns
// packed chunk u (16B): store addr = u*8 elems -> perfectly coalesced.
__global__ void dequant_pack_kernel(const int* __restrict__ qweight,
                                    const int* __restrict__ qzeros,
                                    const float* __restrict__ scales,
                                    unsigned short* __restrict__ wt) {
  unsigned u = blockIdx.x * blockDim.x + threadIdx.x;  // [0, 2^21)
  int lane = u & 63;
  int fs   = (u >> 6) & 7;          // n*2+s
  int n    = fs >> 1, s = fs & 1;
  int tt   = (u >> 9) & 63;
  int wcb  = (u >> 15) & 3;
  int bn   = u >> 17;               // 0..15
  int nn = bn * 256 + wcb * 64 + n * 16 + (lane & 15);
  int kw = tt * 8 + s * 4 + (lane >> 4);   // packed word along K
  int g  = kw >> 4;
  unsigned w = (unsigned)qweight[kw * N_TOT + nn];
  float sc = scales[g * N_TOT + nn];
  unsigned zw = (unsigned)qzeros[g * (N_TOT / 8) + (nn >> 3)];
  float z = (float)(((zw >> ((nn & 7) * 4)) & 15u) + 1u);
  unsigned short o[8];
#pragma unroll
  for (int j = 0; j < 8; ++j) {
    float v = sc * ((float)((w >> (4 * j)) & 15u) - z);
    o[j] = f2bf(v);
  }
  *reinterpret_cast<uint4*>(wt + (size_t)u * 8) =
      *reinterpret_cast<const uint4*>(o);
}

// -- 256x256 GEMM: A via LDS, B direct global->reg from PACKED layout --------
// LDS/tile: 128 b128 reads + 32 KB gll writes (A only); 1 barrier/tile.
__device__ __forceinline__ void gll16(const unsigned short* g, const unsigned short* l) {
  __builtin_amdgcn_global_load_lds(
      (const __attribute__((address_space(1))) void*)(uintptr_t)g,
      (__attribute__((address_space(3))) void*)(uintptr_t)l, 16, 0, 0);
}

__global__ __launch_bounds__(512, 2) void gemm_bpack_kernel(
    const unsigned short* __restrict__ A,   // [M_TOT][K_TOT] bf16
    const unsigned short* __restrict__ Bp,  // packed W^T (see dequant_pack)
    const float* __restrict__ bias,
    float* __restrict__ C) {
  __shared__ __align__(16) unsigned short As[2 * 256 * 64];   // 64 KB, A only

  int bid = blockIdx.x;                    // 512 blocks, 512 % 8 == 0
  int swz = (bid & 7) * 64 + (bid >> 3);   // bijective XCD swizzle (T1)
  int bm = swz & 31, bn = swz >> 5;        // 32 x 16 tiles
  int m0 = bm * 256, n0 = bn * 256;

  int t = threadIdx.x;
  int lane = t & 63;
  int wave = t >> 6;                       // 8 waves
  int wr = wave >> 2, wc = wave & 3;       // 2 (M) x 4 (N)
  int lr = lane & 15, kq = lane >> 4;

  // A staging (round-3 verified, 0 conflicts): physical chunk p = t&7 of rows
  // rowL0, rowL0+64; source pre-permuted j_log = (t&7) ^ (rowL0&7).
  int rowL0 = t >> 3;
  int jlog  = ((t & 7) ^ (rowL0 & 7)) * 8;
  const unsigned short* aG = A + (size_t)(m0 + rowL0) * K_TOT + jlog;

  // A swizzled read base; s half-select composed with XOR (round-2 lesson).
  unsigned rbA = (unsigned)((wr * 128 + lr) * 128 + ((kq * 16) ^ ((lr & 7) << 4)));

  // B packed base: one address register; frag offsets are immediates.
  const unsigned short* bW = Bp + (size_t)(bn * 4 + wc) * 262144 + (size_t)lane * 8;

  f32x4 acc[8][4] = {};
  bf16x8 av[2][2][2];   // [pingpong][mm][s] — next-phase A frags
  bf16x8 bh[2][4][2];   // [tile parity][n][s] — B frags from GLOBAL (coalesced)

#define ASTAGE(tile, h)                                                           \
  do {                                                                            \
    const unsigned short* _g = aG + (size_t)(h) * 128 * K_TOT +                   \
                               (size_t)(tile) * 64;                               \
    const unsigned short* _l = As + ((tile) & 1) * 16384 + (h) * 8192 + t * 8;    \
    gll16(_g, _l);                                                                \
    gll16(_g + (size_t)64 * K_TOT, _l + 4096);                                    \
  } while (0)

#define BLOAD(par, tile)                                                          \
  do {                                                                            \
    const unsigned short* _b = bW + (size_t)(tile) * 4096;                        \
    _Pragma("unroll")                                                             \
    for (int _n = 0; _n < 4; ++_n)                                                \
      _Pragma("unroll")                                                           \
      for (int _s = 0; _s < 2; ++_s)                                              \
        bh[par][_n][_s] = *(const bf16x8*)(_b + (_n * 2 + _s) * 512);             \
  } while (0)

  // Prologue: stage A(0), load B(0) to regs.
  ASTAGE(0, 0);
  ASTAGE(0, 1);
  BLOAD(0, 0);
  asm volatile("s_waitcnt vmcnt(0)" ::: "memory");
  __builtin_amdgcn_s_barrier();
  __builtin_amdgcn_sched_barrier(0);

  // Preload tile-0 phase-0 A frags.
#pragma unroll
  for (int mm = 0; mm < 2; ++mm)
#pragma unroll
    for (int s = 0; s < 2; ++s)
      av[0][mm][s] = *(const bf16x8*)((const char*)As + ((rbA + mm * 2048) ^ (s * 64)));

#pragma unroll 2
  for (int tt = 0; tt < NT; ++tt) {
    const char* aBuf = (const char*)As + (tt & 1) * 32768;

#pragma unroll
    for (int q = 0; q < 4; ++q) {
      // --- MFMA on operands prefetched last phase ---
      __builtin_amdgcn_s_setprio(1);
#pragma unroll
      for (int s = 0; s < 2; ++s)
#pragma unroll
        for (int mm = 0; mm < 2; ++mm)
#pragma unroll
          for (int n = 0; n < 4; ++n)
            acc[2 * q + mm][n] = __builtin_amdgcn_mfma_f32_16x16x32_bf16(
                av[q & 1][mm][s], bh[tt & 1][n][s], acc[2 * q + mm][n], 0, 0, 0);
      __builtin_amdgcn_s_setprio(0);

      // --- prefetch next phase's A frags (A stages write other parity) ---
      if (q < 3) {
#pragma unroll
        for (int mm = 0; mm < 2; ++mm)
#pragma unroll
          for (int s = 0; s < 2; ++s)
            av[(q + 1) & 1][mm][s] = *(const bf16x8*)(
                aBuf + ((rbA + (2 * (q + 1) + mm) * 2048) ^ (s * 64)));
      }

      // --- issue next tile's loads early (3-4 phases of latency cover) ---
      if (q == 0 && tt + 1 < NT) {
        BLOAD((tt + 1) & 1, tt + 1);   // coalesced: 8 x dwordx4, one base
        ASTAGE(tt + 1, 0);
      }
      if (q == 1 && tt + 1 < NT) ASTAGE(tt + 1, 1);

      if (q == 3) {
        // Drain A(t+1) glls + B(t+1) regs — all issued >=2 phases ago.
        // Single barrier/tile: all parity-p ds_reads were lgkm-drained by
        // this wave's q3 MFMA (pre-barrier); parity-p stage writes issue
        // only post-barrier. Max skew = 1 barrier interval -> safe.
        asm volatile("s_waitcnt vmcnt(0)" ::: "memory");
        __builtin_amdgcn_s_barrier();
        __builtin_amdgcn_sched_barrier(0);
        if (tt + 1 < NT) {
          const char* aN = (const char*)As + ((tt + 1) & 1) * 32768;
#pragma unroll
          for (int mm = 0; mm < 2; ++mm)
#pragma unroll
            for (int s = 0; s < 2; ++s)
              av[0][mm][s] = *(const bf16x8*)(aN + ((rbA + mm * 2048) ^ (s * 64)));
        }
      }
    }
  }
#undef ASTAGE
#undef BLOAD

  // Epilogue: C/D layout col=lane&15, row=(lane>>4)*4+reg (m89-verified).
#pragma unroll
  for (int n = 0; n < 4; ++n) {
    int ncol = n0 + wc * 64 + n * 16 + lr;
    float bz = bias[ncol];
#pragma unroll
    for (int m = 0; m < 8; ++m) {
      int mrow = m0 + wr * 128 + m * 16 + kq * 4;
#pragma unroll
      for (int r = 0; r < 4; ++r)
        C[(size_t)(mrow + r) * N_TOT + ncol] = acc[m][n][r] + bz;
    }
  }
}

extern "C" void kernel_launch(void* const* d_in, const int* in_sizes, int n_in,
                              void* d_out, int out_size, void* d_ws, size_t ws_size,
                              hipStream_t stream) {
  const float* x       = (const float*)d_in[0];
  const int*   qweight = (const int*)d_in[1];
  const int*   qzeros  = (const int*)d_in[2];
  const float* scales  = (const float*)d_in[3];
  const float* bias    = (const float*)d_in[4];
  float* out = (float*)d_out;

  const size_t xb_bytes = (size_t)M_TOT * K_TOT * 2;   // 64 MB
  const size_t wt_bytes = (size_t)N_TOT * K_TOT * 2;   // 32 MB
  if (ws_size < xb_bytes + wt_bytes) return;

  unsigned short* Xb = (unsigned short*)d_ws;
  unsigned short* Wt = (unsigned short*)((char*)d_ws + xb_bytes);

  cvt_x_kernel<<<2048, 256, 0, stream>>>(x, Xb, M_TOT * K_TOT);
  dequant_pack_kernel<<<(N_TOT * 512) / 256, 256, 0, stream>>>(qweight, qzeros, scales, Wt);

  dim3 grid((M_TOT / 256) * (N_TOT / 256));  // 512
  gemm_bpack_kernel<<<grid, 512, 0, stream>>>(Xb, Wt, bias, out);
}

// Round 13
// 281.266 us; speedup vs baseline: 1.4739x; 1.0130x over previous
//
#include <hip/hip_runtime.h>
#include <hip/hip_bf16.h>
#include <stdint.h>

// GPTQ 4-bit linear: y = x @ dequant(qweight,qzeros,scales) + bias
// x: [4,2048,4096] fp32 -> M=8192 rows; qweight [512,4096] i32 (8 k-nibbles/word);
// qzeros [32,512] i32 (8 n-nibbles/word, z=nib+1); scales [32,4096] f32; out f32.

#define M_TOT 8192
#define N_TOT 4096
#define K_TOT 4096
#define NT    (K_TOT / 64)   // 64 K-tiles of BK=64

using bf16x8 = __attribute__((ext_vector_type(8))) __bf16;
using f32x4  = __attribute__((ext_vector_type(4))) float;

__device__ __forceinline__ unsigned short f2bf(float f) {
  unsigned u = __builtin_bit_cast(unsigned, f);
  u += 0x7fffu + ((u >> 16) & 1u);   // RNE
  return (unsigned short)(u >> 16);
}

// ---------------- x: fp32 -> bf16 ----------------
__global__ void cvt_x_kernel(const float* __restrict__ x,
                             unsigned short* __restrict__ xb, int n) {
  int stride = gridDim.x * blockDim.x * 8;
  for (int i = (blockIdx.x * blockDim.x + threadIdx.x) * 8; i < n; i += stride) {
    float4 a = *reinterpret_cast<const float4*>(x + i);
    float4 b = *reinterpret_cast<const float4*>(x + i + 4);
    unsigned short o[8] = {f2bf(a.x), f2bf(a.y), f2bf(a.z), f2bf(a.w),
                           f2bf(b.x), f2bf(b.y), f2bf(b.z), f2bf(b.w)};
    *reinterpret_cast<uint4*>(xb + i) = *reinterpret_cast<const uint4*>(o);
  }
}

// -------- dequant -> W^T packed in MFMA fragment order ----------------------
// P[bn][wc][t][n*2+s][lane][j]; GEMM wave (bn,wc) tile t frag (n,s): lane l
// holds W^T[nn][k], nn = bn*256+wc*64+n*16+(l&15), k = t*64+s*32+(l>>4)*8+j.
// Dequant thread u owns packed chunk u (16B) -> stores perfectly coalesced.
__global__ void dequant_pack_kernel(const int* __restrict__ qweight,
                                    const int* __restrict__ qzeros,
                                    const float* __restrict__ scales,
                                    unsigned short* __restrict__ wt) {
  unsigned u = blockIdx.x * blockDim.x + threadIdx.x;  // [0, 2^21)
  int lane = u & 63;
  int fs   = (u >> 6) & 7;          // n*2+s
  int n    = fs >> 1, s = fs & 1;
  int tt   = (u >> 9) & 63;
  int wcb  = (u >> 15) & 3;
  int bn   = u >> 17;               // 0..15
  int nn = bn * 256 + wcb * 64 + n * 16 + (lane & 15);
  int kw = tt * 8 + s * 4 + (lane >> 4);   // packed word along K
  int g  = kw >> 4;
  unsigned w = (unsigned)qweight[kw * N_TOT + nn];
  float sc = scales[g * N_TOT + nn];
  unsigned zw = (unsigned)qzeros[g * (N_TOT / 8) + (nn >> 3)];
  float z = (float)(((zw >> ((nn & 7) * 4)) & 15u) + 1u);
  unsigned short o[8];
#pragma unroll
  for (int j = 0; j < 8; ++j) {
    float v = sc * ((float)((w >> (4 * j)) & 15u) - z);
    o[j] = f2bf(v);
  }
  *reinterpret_cast<uint4*>(wt + (size_t)u * 8) =
      *reinterpret_cast<const uint4*>(o);
}

// -- 256x256 GEMM: A via LDS, B packed global->reg; SGB issue-interleave -----
__device__ __forceinline__ void gll16(const unsigned short* g, const unsigned short* l) {
  __builtin_amdgcn_global_load_lds(
      (const __attribute__((address_space(1))) void*)(uintptr_t)g,
      (__attribute__((address_space(3))) void*)(uintptr_t)l, 16, 0, 0);
}

__global__ __launch_bounds__(512, 2) void gemm_sgb_kernel(
    const unsigned short* __restrict__ A,   // [M_TOT][K_TOT] bf16
    const unsigned short* __restrict__ Bp,  // packed W^T (see dequant_pack)
    const float* __restrict__ bias,
    float* __restrict__ C) {
  __shared__ __align__(16) unsigned short As[2 * 256 * 64];   // 64 KB, A only

  int bid = blockIdx.x;                    // 512 blocks, 512 % 8 == 0
  int swz = (bid & 7) * 64 + (bid >> 3);   // bijective XCD swizzle (T1)
  int bm = swz & 31, bn = swz >> 5;        // 32 x 16 tiles
  int m0 = bm * 256, n0 = bn * 256;

  int t = threadIdx.x;
  int lane = t & 63;
  int wave = t >> 6;                       // 8 waves
  int wr = wave >> 2, wc = wave & 3;       // 2 (M) x 4 (N)
  int lr = lane & 15, kq = lane >> 4;

  // A staging (round-3 verified, 0 conflicts): physical chunk p = t&7 of rows
  // rowL0, rowL0+64; source pre-permuted j_log = (t&7) ^ (rowL0&7).
  int rowL0 = t >> 3;
  int jlog  = ((t & 7) ^ (rowL0 & 7)) * 8;
  const unsigned short* aG = A + (size_t)(m0 + rowL0) * K_TOT + jlog;

  // A swizzled read base; s half-select composed with XOR (round-2 lesson).
  unsigned rbA = (unsigned)((wr * 128 + lr) * 128 + ((kq * 16) ^ ((lr & 7) << 4)));

  // B packed base: one address register; frag offsets are immediates.
  const unsigned short* bW = Bp + (size_t)(bn * 4 + wc) * 262144 + (size_t)lane * 8;

  f32x4 acc[8][4] = {};
  bf16x8 av[2][2][2];   // [pingpong][mm][s] — next-phase A frags
  bf16x8 bh[2][4][2];   // [tile parity][n][s] — B frags from GLOBAL (coalesced)

#define ASTAGE(tile, h)                                                           \
  do {                                                                            \
    const unsigned short* _g = aG + (size_t)(h) * 128 * K_TOT +                   \
                               (size_t)(tile) * 64;                               \
    const unsigned short* _l = As + ((tile) & 1) * 16384 + (h) * 8192 + t * 8;    \
    gll16(_g, _l);                                                                \
    gll16(_g + (size_t)64 * K_TOT, _l + 4096);                                    \
  } while (0)

#define BLOAD(par, tile)                                                          \
  do {                                                                            \
    const unsigned short* _b = bW + (size_t)(tile) * 4096;                        \
    _Pragma("unroll")                                                             \
    for (int _n = 0; _n < 4; ++_n)                                                \
      _Pragma("unroll")                                                           \
      for (int _s = 0; _s < 2; ++_s)                                              \
        bh[par][_n][_s] = *(const bf16x8*)(_b + (_n * 2 + _s) * 512);             \
  } while (0)

  // Prologue: stage A(0), load B(0) to regs.
  ASTAGE(0, 0);
  ASTAGE(0, 1);
  BLOAD(0, 0);
  asm volatile("s_waitcnt vmcnt(0)" ::: "memory");
  __builtin_amdgcn_s_barrier();
  __builtin_amdgcn_sched_barrier(0);

  // Preload tile-0 phase-0 A frags.
#pragma unroll
  for (int mm = 0; mm < 2; ++mm)
#pragma unroll
    for (int s = 0; s < 2; ++s)
      av[0][mm][s] = *(const bf16x8*)((const char*)As + ((rbA + mm * 2048) ^ (s * 64)));

#pragma unroll 2
  for (int tt = 0; tt < NT; ++tt) {
    const char* aBuf = (const char*)As + (tt & 1) * 32768;

#pragma unroll
    for (int q = 0; q < 4; ++q) {
      // --- one scheduling region: 16 MFMA + next-phase A ds_reads,
      //     interleaved at ISSUE level by sched_group_barrier so the matrix
      //     pipe stays fed through each wave's read window (round-13 probe).
      __builtin_amdgcn_s_setprio(1);
#pragma unroll
      for (int s = 0; s < 2; ++s)
#pragma unroll
        for (int mm = 0; mm < 2; ++mm)
#pragma unroll
          for (int n = 0; n < 4; ++n)
            acc[2 * q + mm][n] = __builtin_amdgcn_mfma_f32_16x16x32_bf16(
                av[q & 1][mm][s], bh[tt & 1][n][s], acc[2 * q + mm][n], 0, 0, 0);
      if (q < 3) {
#pragma unroll
        for (int mm = 0; mm < 2; ++mm)
#pragma unroll
          for (int s = 0; s < 2; ++s)
            av[(q + 1) & 1][mm][s] = *(const bf16x8*)(
                aBuf + ((rbA + (2 * (q + 1) + mm) * 2048) ^ (s * 64)));
        // Pin: {2 MFMA, 1 DS_READ} x4, then the remaining 8 MFMA.
#pragma unroll
        for (int i = 0; i < 4; ++i) {
          __builtin_amdgcn_sched_group_barrier(0x008, 2, 0);   // MFMA
          __builtin_amdgcn_sched_group_barrier(0x100, 1, 0);   // DS_READ
        }
        __builtin_amdgcn_sched_group_barrier(0x008, 8, 0);
      }
      __builtin_amdgcn_s_setprio(0);

      // --- issue next tile's loads early (3-4 phases of latency cover) ---
      if (q == 0 && tt + 1 < NT) {
        BLOAD((tt + 1) & 1, tt + 1);   // coalesced: 8 x dwordx4, one base
        ASTAGE(tt + 1, 0);
      }
      if (q == 1 && tt + 1 < NT) ASTAGE(tt + 1, 1);

      if (q == 3) {
        // Drain A(t+1) glls + B(t+1) regs — all issued >=2 phases ago.
        // Single barrier/tile (r10-verified hazard audit).
        asm volatile("s_waitcnt vmcnt(0)" ::: "memory");
        __builtin_amdgcn_s_barrier();
        __builtin_amdgcn_sched_barrier(0);
        if (tt + 1 < NT) {
          const char* aN = (const char*)As + ((tt + 1) & 1) * 32768;
#pragma unroll
          for (int mm = 0; mm < 2; ++mm)
#pragma unroll
            for (int s = 0; s < 2; ++s)
              av[0][mm][s] = *(const bf16x8*)(aN + ((rbA + mm * 2048) ^ (s * 64)));
        }
      }
    }
  }
#undef ASTAGE
#undef BLOAD

  // Epilogue: C/D layout col=lane&15, row=(lane>>4)*4+reg (m89-verified).
#pragma unroll
  for (int n = 0; n < 4; ++n) {
    int ncol = n0 + wc * 64 + n * 16 + lr;
    float bz = bias[ncol];
#pragma unroll
    for (int m = 0; m < 8; ++m) {
      int mrow = m0 + wr * 128 + m * 16 + kq * 4;
#pragma unroll
      for (int r = 0; r < 4; ++r)
        C[(size_t)(mrow + r) * N_TOT + ncol] = acc[m][n][r] + bz;
    }
  }
}

extern "C" void kernel_launch(void* const* d_in, const int* in_sizes, int n_in,
                              void* d_out, int out_size, void* d_ws, size_t ws_size,
                              hipStream_t stream) {
  const float* x       = (const float*)d_in[0];
  const int*   qweight = (const int*)d_in[1];
  const int*   qzeros  = (const int*)d_in[2];
  const float* scales  = (const float*)d_in[3];
  const float* bias    = (const float*)d_in[4];
  float* out = (float*)d_out;

  const size_t xb_bytes = (size_t)M_TOT * K_TOT * 2;   // 64 MB
  const size_t wt_bytes = (size_t)N_TOT * K_TOT * 2;   // 32 MB
  if (ws_size < xb_bytes + wt_bytes) return;

  unsigned short* Xb = (unsigned short*)d_ws;
  unsigned short* Wt = (unsigned short*)((char*)d_ws + xb_bytes);

  cvt_x_kernel<<<2048, 256, 0, stream>>>(x, Xb, M_TOT * K_TOT);
  dequant_pack_kernel<<<(N_TOT * 512) / 256, 256, 0, stream>>>(qweight, qzeros, scales, Wt);

  dim3 grid((M_TOT / 256) * (N_TOT / 256));  // 512
  gemm_sgb_kernel<<<grid, 512, 0, stream>>>(Xb, Wt, bias, out);
}